// Round 20
// baseline (149.434 us; speedup 1.0000x reference)
//
#include <hip/hip_runtime.h>
#include <hip/hip_fp16.h>
#include <cstdint>
#include <cstddef>

// Problem constants (match reference)
#define Bn 4
#define Nn 2048
#define Dn 128
#define OUTn 64
#define Sn 8          // 4 batches x {fwd, rev}
#define MAXDEG 128    // binomial(2048, 1/32): mean 64, sd 7.9; max over 16K rows ~99
#define NITER 3

typedef _Float16 half8 __attribute__((ext_vector_type(8)));
typedef float floatx4 __attribute__((ext_vector_type(4)));

// ---------------------------------------------------------------------------
// deposit low 16 bits of x at bit positions 0,4,8,...,60
__device__ __forceinline__ unsigned long long spread4(unsigned long long x) {
    x &= 0xFFFFull;
    x = (x | (x << 24)) & 0x000000FF000000FFull;
    x = (x | (x << 12)) & 0x000F000F000F000Full;
    x = (x | (x << 6))  & 0x0303030303030303ull;
    x = (x | (x << 3))  & 0x1111111111111111ull;
    return x;
}

// ---------------------------------------------------------------------------
// Blocks [0, 4096): one wave per forward row (b,i): forward adjacency
// (sorted, deterministic), degree, and the column-major bitmask.
// Blocks [4096, 5120): row-organized init: xh = fp16(relu(INPUT[b])) for
// slots b and b+4, AND the iteration-0 attention scalars ah1/ah2.
// Block 5120: WhT[c][k] = fp16(W[k][c]) (one-time transpose+convert) and
// counter reset for the fused reduce/final kernel.
__global__ void fwd_bits_init(const float4* __restrict__ cfg4,
                              unsigned long long* __restrict__ bits,
                              int* __restrict__ adj, int* __restrict__ deg,
                              const float4* __restrict__ in4,
                              __half* __restrict__ xh,
                              const float* __restrict__ W, __half* __restrict__ WhT,
                              const float* __restrict__ w1, const float* __restrict__ b1,
                              const float* __restrict__ w2, const float* __restrict__ b2,
                              float* __restrict__ ah1, float* __restrict__ ah2,
                              unsigned* __restrict__ counter) {
    if (blockIdx.x >= (Bn * Nn) / 4 + (Bn * Nn) / 8) {
        // W transpose+convert: 128 active threads, k-major coalesced reads
        int t = threadIdx.x;
        if (t == 255) *counter = 0;            // reset fused-reduce ticket
        if (t < Dn) {
            for (int k = 0; k < Dn; ++k)
                WhT[(size_t)t * Dn + k] = __float2half(W[(size_t)k * Dn + t]);
        }
        return;
    }
    if (blockIdx.x >= (Bn * Nn) / 4) {
        int blk = blockIdx.x - (Bn * Nn) / 4;         // 0..1023
        int t = threadIdx.x;
        int row = blk * 8 + (t >> 5);                 // [0, Bn*Nn)
        int q   = t & 31;                             // feature quad
        float4 v = in4[(size_t)row * 32 + q];
        v.x = v.x > 0.f ? v.x : 0.f;
        v.y = v.y > 0.f ? v.y : 0.f;
        v.z = v.z > 0.f ? v.z : 0.f;
        v.w = v.w > 0.f ? v.w : 0.f;
        __half2 p0h = __floats2half2_rn(v.x, v.y);
        __half2 p1h = __floats2half2_rn(v.z, v.w);
        uint2 u2;
        u2.x = *(unsigned*)&p0h; u2.y = *(unsigned*)&p1h;
        ((uint2*)xh)[(size_t)row * 32 + q] = u2;
        ((uint2*)xh)[(size_t)(Bn * Nn) * 32 + (size_t)row * 32 + q] = u2;
        const float4* w14 = (const float4*)w1;
        const float4* w24 = (const float4*)w2;
        float4 wa = w14[q], wb = w24[q];
        float p1 = v.x * wa.x + v.y * wa.y + v.z * wa.z + v.w * wa.w;
        float p2 = v.x * wb.x + v.y * wb.y + v.z * wb.z + v.w * wb.w;
        #pragma unroll
        for (int o = 16; o >= 1; o >>= 1) {
            p1 += __shfl_xor(p1, o);
            p2 += __shfl_xor(p2, o);
        }
        if (q == 0) {
            float a1 = p1 + b1[0], a2 = p2 + b2[0];
            ah1[row] = a1; ah1[Bn * Nn + row] = a1;   // fwd slot b, rev slot 4+b
            ah2[row] = a2; ah2[Bn * Nn + row] = a2;
        }
        return;
    }
    int row  = blockIdx.x * 4 + (threadIdx.x >> 6);   // [0, Bn*Nn)
    int lane = threadIdx.x & 63;
    int b = row >> 11;
    int i = row & (Nn - 1);
    const float4* crow = cfg4 + (size_t)row * (Nn / 4);
    int* dst = adj + (size_t)row * MAXDEG;
    int cnt = 0;
    for (int j0 = 0; j0 < Nn; j0 += 256) {
        float4 v = crow[(j0 >> 2) + lane];
        int nib = (v.x != 0.f) | ((v.y != 0.f) << 1) |
                  ((v.z != 0.f) << 2) | ((v.w != 0.f) << 3);
        unsigned long long m0 = __ballot(nib & 1);
        unsigned long long m1 = __ballot(nib & 2);
        unsigned long long m2 = __ballot(nib & 4);
        unsigned long long m3 = __ballot(nib & 8);
        unsigned long long below = (1ull << lane) - 1ull;
        int off = __popcll(m0 & below) + __popcll(m1 & below) +
                  __popcll(m2 & below) + __popcll(m3 & below);
        int total = __popcll(m0) + __popcll(m1) + __popcll(m2) + __popcll(m3);
        int base = cnt + off;
        int col = j0 + 4 * lane;
        if (nib & 1) { if (base < MAXDEG) dst[base] = col;     base++; }
        if (nib & 2) { if (base < MAXDEG) dst[base] = col + 1; base++; }
        if (nib & 4) { if (base < MAXDEG) dst[base] = col + 2; base++; }
        if (nib & 8) { if (base < MAXDEG) dst[base] = col + 3; base++; }
        if (lane < 4) {
            int sh = lane << 4;
            unsigned long long w = spread4(m0 >> sh) | (spread4(m1 >> sh) << 1) |
                                   (spread4(m2 >> sh) << 2) | (spread4(m3 >> sh) << 3);
            int jw = (j0 >> 6) + lane;
            bits[((size_t)(b * 32 + jw)) * Nn + i] = w;
        }
        cnt += total;
    }
    if (lane == 0) deg[row] = (cnt < MAXDEG ? cnt : MAXDEG);
}

// ---------------------------------------------------------------------------
// MFMA gemm tile: one wave computes one 16x16 output tile of xw = xh @ W
// over K=128 via 4x mfma_f32_16x16x32_f16. Fragment layout per learn_hip
// m92/m97 (A,B: lane m/n = l&15, k = 8*(l>>4)+e, 16B contiguous loads from
// row-major xh / WhT) and m89 (C/D: col = l&15, row = 4*(l>>4)+reg).
__device__ __forceinline__ void gemm_tile_mfma(const __half* __restrict__ xh,
                                               const __half* __restrict__ WhT,
                                               __half* __restrict__ xwh, int tile) {
    int lane = threadIdx.x & 63;
    int rowTile = tile >> 3, colTile = tile & 7;
    int mn = lane & 15, kseg = lane >> 4;
    const uint4* Arow = (const uint4*)(xh + ((size_t)(rowTile * 16 + mn)) * Dn);
    const uint4* Brow = (const uint4*)(WhT + ((size_t)(colTile * 16 + mn)) * Dn);
    floatx4 c = {0.f, 0.f, 0.f, 0.f};
    #pragma unroll
    for (int ks = 0; ks < 4; ++ks) {
        uint4 au = Arow[ks * 4 + kseg];    // k0 = ks*32 + kseg*8
        uint4 bu = Brow[ks * 4 + kseg];
        half8 a = *(half8*)&au;
        half8 b = *(half8*)&bu;
        c = __builtin_amdgcn_mfma_f32_16x16x32_f16(a, b, c, 0, 0, 0);
    }
    int row = (lane >> 4) * 4;
    __half* dst = xwh + ((size_t)(rowTile * 16 + row)) * Dn + colTile * 16 + mn;
    #pragma unroll
    for (int rg = 0; rg < 4; ++rg)
        dst[(size_t)rg * Dn] = __float2half(c[rg]);
}

// ---------------------------------------------------------------------------
// it=0 merged launch: blocks [0,2048) = MFMA gemm (4 tiles/block);
// blocks [2048, 4096): reverse adjacency, 4 waves x 1 reverse row each
// (2048 blocks x 4 = all 8192 reverse rows):
// read plane bits[b][j>>6][*] contiguously; ballot-compact ascending i.
__global__ void gemm_rev(const __half* __restrict__ xh, const __half* __restrict__ WhT,
                         __half* __restrict__ xwh,
                         const unsigned long long* __restrict__ bits,
                         int* __restrict__ adj, int* __restrict__ deg) {
    if (blockIdx.x < 2048) {
        gemm_tile_mfma(xh, WhT, xwh, blockIdx.x * 4 + (threadIdx.x >> 6));
        return;
    }
    int r    = (blockIdx.x - 2048) * 4 + (threadIdx.x >> 6);  // [0, Bn*Nn)
    int lane = threadIdx.x & 63;
    int b = r >> 11;
    int j = r & (Nn - 1);
    const unsigned long long* col = bits + ((size_t)(b * 32 + (j >> 6))) * Nn;
    int bit = j & 63;
    int out_r = (Bn + b) * Nn + j;
    int* dst = adj + (size_t)out_r * MAXDEG;
    int cnt = 0;
    for (int i0 = 0; i0 < Nn; i0 += 64) {
        unsigned long long word = col[i0 + lane];
        bool e = (word >> bit) & 1;
        unsigned long long m = __ballot(e);
        if (e) {
            int pos = cnt + __popcll(m & ((1ull << lane) - 1ull));
            if (pos < MAXDEG) dst[pos] = i0 + lane;
        }
        cnt += __popcll(m);
    }
    if (lane == 0) deg[out_r] = (cnt < MAXDEG ? cnt : MAXDEG);
}

// ---------------------------------------------------------------------------
// Standalone MFMA gemm (iterations 1..NITER-1): 2048 blocks x 4 tiles.
__global__ void gemm_mfma(const __half* __restrict__ xh, const __half* __restrict__ WhT,
                          __half* __restrict__ xwh) {
    gemm_tile_mfma(xh, WhT, xwh, blockIdx.x * 4 + (threadIdx.x >> 6));
}

// ---------------------------------------------------------------------------
// Fused: masked softmax + sparse aggregate of fp16 xw (__hfma2 packed MACs)
// + residual + ELU + next-iteration ah1/ah2 (double-buffered). State lives
// ONLY in fp16 xh (row-private read->write). ONE WAVE PER ROW, no barriers;
// 16-neighbor gather (R16 geometry — deeper unrolls regressed).
// All-64-lane epilogue via same-wave LDS redistribution.
__global__ __launch_bounds__(256) void attn_agg(
        __half* __restrict__ xh,
        const __half* __restrict__ xwh,
        const int* __restrict__ adj, const int* __restrict__ deg,
        const float* __restrict__ ah1r, const float* __restrict__ ah2r,
        float* __restrict__ ah1w, float* __restrict__ ah2w,
        const float* __restrict__ gw1, const float* __restrict__ gb1,
        const float* __restrict__ gw2, const float* __restrict__ gb2) {
    int w    = threadIdx.x >> 6;       // wave 0..3
    int lane = threadIdx.x & 63;
    int s = blockIdx.x & 7;
    int i = (blockIdx.x >> 3) * 4 + w;
    int r = s * Nn + i;

    __shared__ float2 pn[4][MAXDEG];   // per-wave (p, j) slab
    __shared__ float  aggF[4][Dn];     // per-wave folded accumulator

    int d = deg[r]; if (d > MAXDEG) d = MAXDEG;

    // ---- softmax over neighbor list (this wave, 64 lanes) ----
    float a1 = ah1r[r];
    const int* al = adj + (size_t)r * MAXDEG;
    const float* ah2s = ah2r + (size_t)s * Nn;
    int jlo = 0, jhi = 0;
    float elo = -INFINITY, ehi = -INFINITY;
    if (lane < d) {
        jlo = al[lane];
        float e = a1 + ah2s[jlo];
        elo = e > 0.f ? e : 0.2f * e;              // leaky_relu(0.2)
    }
    if (lane + 64 < d) {
        jhi = al[lane + 64];
        float e = a1 + ah2s[jhi];
        ehi = e > 0.f ? e : 0.2f * e;
    }
    float m = fmaxf(elo, ehi);
    #pragma unroll
    for (int o = 32; o > 0; o >>= 1) m = fmaxf(m, __shfl_xor(m, o));
    float exlo = (lane < d)      ? __expf(elo - m) : 0.f;
    float exhi = (lane + 64 < d) ? __expf(ehi - m) : 0.f;
    float sum = exlo + exhi;
    #pragma unroll
    for (int o = 32; o > 0; o >>= 1) sum += __shfl_xor(sum, o);
    float inv = (d > 0) ? 1.0f / sum : 0.f;

    // publish (p, j) — all 128 entries written (zero-padded past d)
    pn[w][lane]      = make_float2(exlo, __int_as_float(jlo));
    pn[w][lane + 64] = make_float2(exhi, __int_as_float(jhi));
    // no __syncthreads: same-wave LDS write->read, compiler emits lgkmcnt

    // ---- sparse aggregate: group g = lane>>4 handles neighbors k = 4t+g;
    //      lane f = lane&15 owns features 8f..8f+7 (one uint4 of fp16) ----
    const uint4* xwu = (const uint4*)(xwh + (size_t)s * Nn * Dn);  // 16/row
    int g = lane >> 4;
    int f = lane & 15;
    __half2 acc2[4];
    #pragma unroll
    for (int e = 0; e < 4; ++e) acc2[e] = __halves2half2(__float2half(0.f), __float2half(0.f));
    int dpad = (d + 15) & ~15;
    for (int base = 0; base < dpad; base += 16) {
        float2 q[4];
        uint4  v[4];
        #pragma unroll
        for (int t = 0; t < 4; ++t) q[t] = pn[w][base + 4 * t + g];
        #pragma unroll
        for (int t = 0; t < 4; ++t)
            v[t] = xwu[(size_t)__float_as_int(q[t].y) * 16 + f];
        #pragma unroll
        for (int t = 0; t < 4; ++t) {
            __half   ph = __float2half(q[t].x);
            __half2  p2 = __halves2half2(ph, ph);
            const __half2* hh = (const __half2*)&v[t];
            acc2[0] = __hfma2(p2, hh[0], acc2[0]);
            acc2[1] = __hfma2(p2, hh[1], acc2[1]);
            acc2[2] = __hfma2(p2, hh[2], acc2[2]);
            acc2[3] = __hfma2(p2, hh[3], acc2[3]);
        }
    }
    // convert to fp32, then fold the 4 groups across lanes
    float2 f0 = __half22float2(acc2[0]);
    float2 f1 = __half22float2(acc2[1]);
    float2 f2 = __half22float2(acc2[2]);
    float2 f3 = __half22float2(acc2[3]);
    float accA[4] = { f0.x, f0.y, f1.x, f1.y };
    float accB[4] = { f2.x, f2.y, f3.x, f3.y };
    #pragma unroll
    for (int e = 0; e < 4; ++e) {
        accA[e] += __shfl_xor(accA[e], 16);
        accA[e] += __shfl_xor(accA[e], 32);
        accB[e] += __shfl_xor(accB[e], 16);
        accB[e] += __shfl_xor(accB[e], 32);
    }

    // redistribute folded acc to all lanes (feature index 8f+e), same-wave LDS
    if (lane < 16) {
        #pragma unroll
        for (int e = 0; e < 4; ++e) {
            aggF[w][8 * lane + e]     = accA[e];
            aggF[w][8 * lane + 4 + e] = accB[e];
        }
    }

    // ---- all-lane epilogue: cols c0 = lane, c1 = lane+64 ----
    float a0  = aggF[w][lane];
    float a1v = aggF[w][lane + 64];
    size_t xbase = (size_t)r * Dn;
    float v0 = __half2float(xh[xbase + lane]);
    float v1 = __half2float(xh[xbase + lane + 64]);
    float s0 = v0 + a0 * inv;
    float s1 = v1 + a1v * inv;
    s0 = s0 > 0.f ? s0 : (expf(s0) - 1.f);
    s1 = s1 > 0.f ? s1 : (expf(s1) - 1.f);
    xh[xbase + lane]      = __float2half(s0);
    xh[xbase + lane + 64] = __float2half(s1);

    // ---- next-iteration ah1/ah2 (full-wave reduce) ----
    float p1 = s0 * gw1[lane] + s1 * gw1[lane + 64];
    float p2 = s0 * gw2[lane] + s1 * gw2[lane + 64];
    #pragma unroll
    for (int o = 32; o > 0; o >>= 1) {
        p1 += __shfl_xor(p1, o);
        p2 += __shfl_xor(p2, o);
    }
    if (lane == 0) {
        ah1w[r] = p1 + gb1[0];
        ah2w[r] = p2 + gb2[0];
    }
}

// ---------------------------------------------------------------------------
// Fused reduce + final: 128 blocks compute partials (32 chunks of 64 rows per
// batch, fwd+rev fused, fp32 accumulate); the LAST block (device-scope ticket)
// sums the fixed-layout partials and applies the @Wout epilogue.
// Deterministic: partial assignment and the final summation order are fixed.
__global__ void reduce_final(const __half* __restrict__ xh, float* __restrict__ part,
                             unsigned* __restrict__ counter,
                             const float* __restrict__ Wout, const float* __restrict__ bout,
                             float* __restrict__ out) {
    int b = blockIdx.x >> 5;
    int c = blockIdx.x & 31;
    int tid = threadIdx.x;                     // 0..127 = d
    const __half* xf = xh + ((size_t)(b * Nn) + c * 64) * Dn;
    const __half* xr = xh + ((size_t)((4 + b) * Nn) + c * 64) * Dn;
    float sv = 0.f;
    for (int i = 0; i < 64; ++i)
        sv += __half2float(xf[(size_t)i * Dn + tid]) +
              __half2float(xr[(size_t)i * Dn + tid]);
    part[(size_t)blockIdx.x * Dn + tid] = sv;

    // last-block completion
    __threadfence();
    __shared__ unsigned ticket;
    __syncthreads();
    if (tid == 0) ticket = atomicAdd(counter, 1u);
    __syncthreads();
    if (ticket != Bn * 32 - 1) return;
    __threadfence();

    __shared__ float mid[Dn];
    for (int bb = 0; bb < Bn; ++bb) {
        float s2 = 0.f;
        for (int cc = 0; cc < 32; ++cc)
            s2 += part[(size_t)(bb * 32 + cc) * Dn + tid];
        mid[tid] = s2;
        __syncthreads();
        if (tid < OUTn) {
            float o = bout[tid];
            #pragma unroll 4
            for (int k = 0; k < Dn; ++k) o = fmaf(mid[k], Wout[k * OUTn + tid], o);
            out[bb * OUTn + tid] = o;
        }
        __syncthreads();
    }
}

// ---------------------------------------------------------------------------
extern "C" void kernel_launch(void* const* d_in, const int* in_sizes, int n_in,
                              void* d_out, int out_size, void* d_ws, size_t ws_size,
                              hipStream_t stream) {
    const float* INPUT = (const float*)d_in[0];
    const float* CFG   = (const float*)d_in[1];
    // d_in[2] = LFG, unused by the forward pass
    const float* w1    = (const float*)d_in[3];
    const float* b1    = (const float*)d_in[4];
    const float* w2    = (const float*)d_in[5];
    const float* b2    = (const float*)d_in[6];
    const float* Wm    = (const float*)d_in[7];
    const float* Wout  = (const float*)d_in[8];
    const float* bout  = (const float*)d_in[9];
    float* out = (float*)d_out;

    // workspace layout (~18.7 MB)
    __half* xh   = (__half*)d_ws;                         // Sn*Nn*Dn   (4 MB)
    __half* xwh  = xh + (size_t)Sn * Nn * Dn;             // Sn*Nn*Dn   (4 MB)
    __half* WhT  = xwh + (size_t)Sn * Nn * Dn;            // Dn*Dn      (32 KB)
    int*    adj  = (int*)(WhT + (size_t)Dn * Dn);         // Sn*Nn*MAXDEG (8 MB)
    int*    deg  = adj + (size_t)Sn * Nn * MAXDEG;        // Sn*Nn
    float*  ah1a = (float*)(deg + Sn * Nn);               // Sn*Nn
    float*  ah2a = ah1a + Sn * Nn;                        // Sn*Nn
    float*  ah1b = ah2a + Sn * Nn;                        // Sn*Nn
    float*  ah2b = ah1b + Sn * Nn;                        // Sn*Nn
    float*  part = ah2b + Sn * Nn;                        // Bn*32*Dn
    unsigned long long* bits = (unsigned long long*)(part + Bn * 32 * Dn); // 2 MB
    unsigned* counter = (unsigned*)(bits + (size_t)Bn * 32 * Nn);

    fwd_bits_init<<<(Bn * Nn) / 4 + (Bn * Nn) / 8 + 1, 256, 0, stream>>>(
        (const float4*)CFG, bits, adj, deg, (const float4*)INPUT,
        xh, Wm, WhT, w1, b1, w2, b2, ah1a, ah2a, counter);

    for (int it = 0; it < NITER; ++it) {
        if (it == 0) {
            gemm_rev<<<4096, 256, 0, stream>>>(xh, WhT, xwh, bits, adj, deg);
        } else {
            gemm_mfma<<<2048, 256, 0, stream>>>(xh, WhT, xwh);
        }
        const float* r1 = (it & 1) ? ah1b : ah1a;
        const float* r2 = (it & 1) ? ah2b : ah2a;
        float* w1p = (it & 1) ? ah1a : ah1b;
        float* w2p = (it & 1) ? ah2a : ah2b;
        attn_agg<<<(Sn * Nn) / 4, 256, 0, stream>>>(
            xh, xwh, adj, deg, r1, r2, w1p, w2p, w1, b1, w2, b2);
    }

    reduce_final<<<Bn * 32, 128, 0, stream>>>(xh, part, counter, Wout, bout, out);
}

// Round 21
// 132.008 us; speedup vs baseline: 1.1320x; 1.1320x over previous
//
#include <hip/hip_runtime.h>
#include <hip/hip_fp16.h>
#include <cstdint>
#include <cstddef>

// Problem constants (match reference)
#define Bn 4
#define Nn 2048
#define Dn 128
#define OUTn 64
#define Sn 8          // 4 batches x {fwd, rev}
#define MAXDEG 128    // binomial(2048, 1/32): mean 64, sd 7.9; max over 16K rows ~99
#define NITER 3

typedef _Float16 half8 __attribute__((ext_vector_type(8)));
typedef float floatx4 __attribute__((ext_vector_type(4)));

// ---------------------------------------------------------------------------
// deposit low 16 bits of x at bit positions 0,4,8,...,60
__device__ __forceinline__ unsigned long long spread4(unsigned long long x) {
    x &= 0xFFFFull;
    x = (x | (x << 24)) & 0x000000FF000000FFull;
    x = (x | (x << 12)) & 0x000F000F000F000Full;
    x = (x | (x << 6))  & 0x0303030303030303ull;
    x = (x | (x << 3))  & 0x1111111111111111ull;
    return x;
}

// ---------------------------------------------------------------------------
// Blocks [0, 4096): one wave per forward row (b,i): forward adjacency
// (sorted, deterministic), degree, and the column-major bitmask.
// Blocks [4096, 5120): row-organized init: xh = fp16(relu(INPUT[b])) for
// slots b and b+4, AND the iteration-0 attention scalars ah1/ah2.
// Block 5120: WhT[c][k] = fp16(W[k][c])  (one-time transpose+convert).
__global__ void fwd_bits_init(const float4* __restrict__ cfg4,
                              unsigned long long* __restrict__ bits,
                              int* __restrict__ adj, int* __restrict__ deg,
                              const float4* __restrict__ in4,
                              __half* __restrict__ xh,
                              const float* __restrict__ W, __half* __restrict__ WhT,
                              const float* __restrict__ w1, const float* __restrict__ b1,
                              const float* __restrict__ w2, const float* __restrict__ b2,
                              float* __restrict__ ah1, float* __restrict__ ah2) {
    if (blockIdx.x >= (Bn * Nn) / 4 + (Bn * Nn) / 8) {
        // W transpose+convert: 128 active threads, k-major coalesced reads
        int t = threadIdx.x;
        if (t < Dn) {
            for (int k = 0; k < Dn; ++k)
                WhT[(size_t)t * Dn + k] = __float2half(W[(size_t)k * Dn + t]);
        }
        return;
    }
    if (blockIdx.x >= (Bn * Nn) / 4) {
        int blk = blockIdx.x - (Bn * Nn) / 4;         // 0..1023
        int t = threadIdx.x;
        int row = blk * 8 + (t >> 5);                 // [0, Bn*Nn)
        int q   = t & 31;                             // feature quad
        float4 v = in4[(size_t)row * 32 + q];
        v.x = v.x > 0.f ? v.x : 0.f;
        v.y = v.y > 0.f ? v.y : 0.f;
        v.z = v.z > 0.f ? v.z : 0.f;
        v.w = v.w > 0.f ? v.w : 0.f;
        __half2 p0h = __floats2half2_rn(v.x, v.y);
        __half2 p1h = __floats2half2_rn(v.z, v.w);
        uint2 u2;
        u2.x = *(unsigned*)&p0h; u2.y = *(unsigned*)&p1h;
        ((uint2*)xh)[(size_t)row * 32 + q] = u2;
        ((uint2*)xh)[(size_t)(Bn * Nn) * 32 + (size_t)row * 32 + q] = u2;
        const float4* w14 = (const float4*)w1;
        const float4* w24 = (const float4*)w2;
        float4 wa = w14[q], wb = w24[q];
        float p1 = v.x * wa.x + v.y * wa.y + v.z * wa.z + v.w * wa.w;
        float p2 = v.x * wb.x + v.y * wb.y + v.z * wb.z + v.w * wb.w;
        #pragma unroll
        for (int o = 16; o >= 1; o >>= 1) {
            p1 += __shfl_xor(p1, o);
            p2 += __shfl_xor(p2, o);
        }
        if (q == 0) {
            float a1 = p1 + b1[0], a2 = p2 + b2[0];
            ah1[row] = a1; ah1[Bn * Nn + row] = a1;   // fwd slot b, rev slot 4+b
            ah2[row] = a2; ah2[Bn * Nn + row] = a2;
        }
        return;
    }
    int row  = blockIdx.x * 4 + (threadIdx.x >> 6);   // [0, Bn*Nn)
    int lane = threadIdx.x & 63;
    int b = row >> 11;
    int i = row & (Nn - 1);
    const float4* crow = cfg4 + (size_t)row * (Nn / 4);
    int* dst = adj + (size_t)row * MAXDEG;
    int cnt = 0;
    for (int j0 = 0; j0 < Nn; j0 += 256) {
        float4 v = crow[(j0 >> 2) + lane];
        int nib = (v.x != 0.f) | ((v.y != 0.f) << 1) |
                  ((v.z != 0.f) << 2) | ((v.w != 0.f) << 3);
        unsigned long long m0 = __ballot(nib & 1);
        unsigned long long m1 = __ballot(nib & 2);
        unsigned long long m2 = __ballot(nib & 4);
        unsigned long long m3 = __ballot(nib & 8);
        unsigned long long below = (1ull << lane) - 1ull;
        int off = __popcll(m0 & below) + __popcll(m1 & below) +
                  __popcll(m2 & below) + __popcll(m3 & below);
        int total = __popcll(m0) + __popcll(m1) + __popcll(m2) + __popcll(m3);
        int base = cnt + off;
        int col = j0 + 4 * lane;
        if (nib & 1) { if (base < MAXDEG) dst[base] = col;     base++; }
        if (nib & 2) { if (base < MAXDEG) dst[base] = col + 1; base++; }
        if (nib & 4) { if (base < MAXDEG) dst[base] = col + 2; base++; }
        if (nib & 8) { if (base < MAXDEG) dst[base] = col + 3; base++; }
        if (lane < 4) {
            int sh = lane << 4;
            unsigned long long w = spread4(m0 >> sh) | (spread4(m1 >> sh) << 1) |
                                   (spread4(m2 >> sh) << 2) | (spread4(m3 >> sh) << 3);
            int jw = (j0 >> 6) + lane;
            bits[((size_t)(b * 32 + jw)) * Nn + i] = w;
        }
        cnt += total;
    }
    if (lane == 0) deg[row] = (cnt < MAXDEG ? cnt : MAXDEG);
}

// ---------------------------------------------------------------------------
// MFMA gemm tile: one wave computes one 16x16 output tile of xw = xh @ W
// over K=128 via 4x mfma_f32_16x16x32_f16. Fragment layout per learn_hip
// m92/m97 (A,B: lane m/n = l&15, k = 8*(l>>4)+e, 16B contiguous loads from
// row-major xh / WhT) and m89 (C/D: col = l&15, row = 4*(l>>4)+reg).
__device__ __forceinline__ void gemm_tile_mfma(const __half* __restrict__ xh,
                                               const __half* __restrict__ WhT,
                                               __half* __restrict__ xwh, int tile) {
    int lane = threadIdx.x & 63;
    int rowTile = tile >> 3, colTile = tile & 7;
    int mn = lane & 15, kseg = lane >> 4;
    const uint4* Arow = (const uint4*)(xh + ((size_t)(rowTile * 16 + mn)) * Dn);
    const uint4* Brow = (const uint4*)(WhT + ((size_t)(colTile * 16 + mn)) * Dn);
    floatx4 c = {0.f, 0.f, 0.f, 0.f};
    #pragma unroll
    for (int ks = 0; ks < 4; ++ks) {
        uint4 au = Arow[ks * 4 + kseg];    // k0 = ks*32 + kseg*8
        uint4 bu = Brow[ks * 4 + kseg];
        half8 a = *(half8*)&au;
        half8 b = *(half8*)&bu;
        c = __builtin_amdgcn_mfma_f32_16x16x32_f16(a, b, c, 0, 0, 0);
    }
    int row = (lane >> 4) * 4;
    __half* dst = xwh + ((size_t)(rowTile * 16 + row)) * Dn + colTile * 16 + mn;
    #pragma unroll
    for (int rg = 0; rg < 4; ++rg)
        dst[(size_t)rg * Dn] = __float2half(c[rg]);
}

// ---------------------------------------------------------------------------
// it=0 merged launch: blocks [0,2048) = MFMA gemm (4 tiles/block);
// blocks [2048, 4096): reverse adjacency, 4 waves x 1 reverse row each
// (2048 blocks x 4 = all 8192 reverse rows):
// read plane bits[b][j>>6][*] contiguously; ballot-compact ascending i.
__global__ void gemm_rev(const __half* __restrict__ xh, const __half* __restrict__ WhT,
                         __half* __restrict__ xwh,
                         const unsigned long long* __restrict__ bits,
                         int* __restrict__ adj, int* __restrict__ deg) {
    if (blockIdx.x < 2048) {
        gemm_tile_mfma(xh, WhT, xwh, blockIdx.x * 4 + (threadIdx.x >> 6));
        return;
    }
    int r    = (blockIdx.x - 2048) * 4 + (threadIdx.x >> 6);  // [0, Bn*Nn)
    int lane = threadIdx.x & 63;
    int b = r >> 11;
    int j = r & (Nn - 1);
    const unsigned long long* col = bits + ((size_t)(b * 32 + (j >> 6))) * Nn;
    int bit = j & 63;
    int out_r = (Bn + b) * Nn + j;
    int* dst = adj + (size_t)out_r * MAXDEG;
    int cnt = 0;
    for (int i0 = 0; i0 < Nn; i0 += 64) {
        unsigned long long word = col[i0 + lane];
        bool e = (word >> bit) & 1;
        unsigned long long m = __ballot(e);
        if (e) {
            int pos = cnt + __popcll(m & ((1ull << lane) - 1ull));
            if (pos < MAXDEG) dst[pos] = i0 + lane;
        }
        cnt += __popcll(m);
    }
    if (lane == 0) deg[out_r] = (cnt < MAXDEG ? cnt : MAXDEG);
}

// ---------------------------------------------------------------------------
// Standalone MFMA gemm (iterations 1..NITER-1): 2048 blocks x 4 tiles.
__global__ void gemm_mfma(const __half* __restrict__ xh, const __half* __restrict__ WhT,
                          __half* __restrict__ xwh) {
    gemm_tile_mfma(xh, WhT, xwh, blockIdx.x * 4 + (threadIdx.x >> 6));
}

// ---------------------------------------------------------------------------
// Fused: masked softmax + sparse aggregate of fp16 xw (__hfma2 packed MACs)
// + residual + ELU + next-iteration ah1/ah2 (double-buffered). State lives
// ONLY in fp16 xh (row-private read->write). ONE WAVE PER ROW, no barriers;
// 16-neighbor gather (R16 geometry — deeper unrolls regressed).
// All-64-lane epilogue via same-wave LDS redistribution.
__global__ __launch_bounds__(256) void attn_agg(
        __half* __restrict__ xh,
        const __half* __restrict__ xwh,
        const int* __restrict__ adj, const int* __restrict__ deg,
        const float* __restrict__ ah1r, const float* __restrict__ ah2r,
        float* __restrict__ ah1w, float* __restrict__ ah2w,
        const float* __restrict__ gw1, const float* __restrict__ gb1,
        const float* __restrict__ gw2, const float* __restrict__ gb2) {
    int w    = threadIdx.x >> 6;       // wave 0..3
    int lane = threadIdx.x & 63;
    int s = blockIdx.x & 7;
    int i = (blockIdx.x >> 3) * 4 + w;
    int r = s * Nn + i;

    __shared__ float2 pn[4][MAXDEG];   // per-wave (p, j) slab
    __shared__ float  aggF[4][Dn];     // per-wave folded accumulator

    int d = deg[r]; if (d > MAXDEG) d = MAXDEG;

    // ---- softmax over neighbor list (this wave, 64 lanes) ----
    float a1 = ah1r[r];
    const int* al = adj + (size_t)r * MAXDEG;
    const float* ah2s = ah2r + (size_t)s * Nn;
    int jlo = 0, jhi = 0;
    float elo = -INFINITY, ehi = -INFINITY;
    if (lane < d) {
        jlo = al[lane];
        float e = a1 + ah2s[jlo];
        elo = e > 0.f ? e : 0.2f * e;              // leaky_relu(0.2)
    }
    if (lane + 64 < d) {
        jhi = al[lane + 64];
        float e = a1 + ah2s[jhi];
        ehi = e > 0.f ? e : 0.2f * e;
    }
    float m = fmaxf(elo, ehi);
    #pragma unroll
    for (int o = 32; o > 0; o >>= 1) m = fmaxf(m, __shfl_xor(m, o));
    float exlo = (lane < d)      ? __expf(elo - m) : 0.f;
    float exhi = (lane + 64 < d) ? __expf(ehi - m) : 0.f;
    float sum = exlo + exhi;
    #pragma unroll
    for (int o = 32; o > 0; o >>= 1) sum += __shfl_xor(sum, o);
    float inv = (d > 0) ? 1.0f / sum : 0.f;

    // publish (p, j) — all 128 entries written (zero-padded past d)
    pn[w][lane]      = make_float2(exlo, __int_as_float(jlo));
    pn[w][lane + 64] = make_float2(exhi, __int_as_float(jhi));
    // no __syncthreads: same-wave LDS write->read, compiler emits lgkmcnt

    // ---- sparse aggregate: group g = lane>>4 handles neighbors k = 4t+g;
    //      lane f = lane&15 owns features 8f..8f+7 (one uint4 of fp16) ----
    const uint4* xwu = (const uint4*)(xwh + (size_t)s * Nn * Dn);  // 16/row
    int g = lane >> 4;
    int f = lane & 15;
    __half2 acc2[4];
    #pragma unroll
    for (int e = 0; e < 4; ++e) acc2[e] = __halves2half2(__float2half(0.f), __float2half(0.f));
    int dpad = (d + 15) & ~15;
    for (int base = 0; base < dpad; base += 16) {
        float2 q[4];
        uint4  v[4];
        #pragma unroll
        for (int t = 0; t < 4; ++t) q[t] = pn[w][base + 4 * t + g];
        #pragma unroll
        for (int t = 0; t < 4; ++t)
            v[t] = xwu[(size_t)__float_as_int(q[t].y) * 16 + f];
        #pragma unroll
        for (int t = 0; t < 4; ++t) {
            __half   ph = __float2half(q[t].x);
            __half2  p2 = __halves2half2(ph, ph);
            const __half2* hh = (const __half2*)&v[t];
            acc2[0] = __hfma2(p2, hh[0], acc2[0]);
            acc2[1] = __hfma2(p2, hh[1], acc2[1]);
            acc2[2] = __hfma2(p2, hh[2], acc2[2]);
            acc2[3] = __hfma2(p2, hh[3], acc2[3]);
        }
    }
    // convert to fp32, then fold the 4 groups across lanes
    float2 f0 = __half22float2(acc2[0]);
    float2 f1 = __half22float2(acc2[1]);
    float2 f2 = __half22float2(acc2[2]);
    float2 f3 = __half22float2(acc2[3]);
    float accA[4] = { f0.x, f0.y, f1.x, f1.y };
    float accB[4] = { f2.x, f2.y, f3.x, f3.y };
    #pragma unroll
    for (int e = 0; e < 4; ++e) {
        accA[e] += __shfl_xor(accA[e], 16);
        accA[e] += __shfl_xor(accA[e], 32);
        accB[e] += __shfl_xor(accB[e], 16);
        accB[e] += __shfl_xor(accB[e], 32);
    }

    // redistribute folded acc to all lanes (feature index 8f+e), same-wave LDS
    if (lane < 16) {
        #pragma unroll
        for (int e = 0; e < 4; ++e) {
            aggF[w][8 * lane + e]     = accA[e];
            aggF[w][8 * lane + 4 + e] = accB[e];
        }
    }

    // ---- all-lane epilogue: cols c0 = lane, c1 = lane+64 ----
    float a0  = aggF[w][lane];
    float a1v = aggF[w][lane + 64];
    size_t xbase = (size_t)r * Dn;
    float v0 = __half2float(xh[xbase + lane]);
    float v1 = __half2float(xh[xbase + lane + 64]);
    float s0 = v0 + a0 * inv;
    float s1 = v1 + a1v * inv;
    s0 = s0 > 0.f ? s0 : (expf(s0) - 1.f);
    s1 = s1 > 0.f ? s1 : (expf(s1) - 1.f);
    xh[xbase + lane]      = __float2half(s0);
    xh[xbase + lane + 64] = __float2half(s1);

    // ---- next-iteration ah1/ah2 (full-wave reduce) ----
    float p1 = s0 * gw1[lane] + s1 * gw1[lane + 64];
    float p2 = s0 * gw2[lane] + s1 * gw2[lane + 64];
    #pragma unroll
    for (int o = 32; o > 0; o >>= 1) {
        p1 += __shfl_xor(p1, o);
        p2 += __shfl_xor(p2, o);
    }
    if (lane == 0) {
        ah1w[r] = p1 + gb1[0];
        ah2w[r] = p2 + gb2[0];
    }
}

// ---------------------------------------------------------------------------
// Stage-1 reduction over rows (fp16 state): 32 chunks of 64 rows per batch,
// fwd+rev fused; accumulate fp32. __half2-vectorized loads (G13): thread t
// owns column pair p = t&63 and row half h = t>>6 (rows 32h..32h+31);
// halves folded through a 512B LDS exchange.
__global__ void reduce_partial(const __half* __restrict__ xh, float* __restrict__ part) {
    int b = blockIdx.x >> 5;
    int c = blockIdx.x & 31;
    int tid = threadIdx.x;                     // 128 threads
    int p = tid & 63;                          // column pair (cols 2p, 2p+1)
    int h = tid >> 6;                          // row half
    const __half2* xf = (const __half2*)(xh + ((size_t)(b * Nn) + c * 64 + h * 32) * Dn);
    const __half2* xr = (const __half2*)(xh + ((size_t)((4 + b) * Nn) + c * 64 + h * 32) * Dn);
    float2 sv = make_float2(0.f, 0.f);
    for (int i = 0; i < 32; ++i) {
        float2 af = __half22float2(xf[(size_t)i * 64 + p]);
        float2 ar = __half22float2(xr[(size_t)i * 64 + p]);
        sv.x += af.x + ar.x;
        sv.y += af.y + ar.y;
    }
    __shared__ float2 fold[64];
    if (h == 1) fold[p] = sv;
    __syncthreads();
    if (h == 0) {
        float2 o = fold[p];
        sv.x += o.x;
        sv.y += o.y;
        ((float2*)part)[(size_t)blockIdx.x * 64 + p] = sv;
    }
}

// ---------------------------------------------------------------------------
// Stage-2: mid[b] = sum of partials; out[b] = mid @ Wout + bout
__global__ void final_out(const float* __restrict__ part,
                          const float* __restrict__ Wout, const float* __restrict__ bout,
                          float* __restrict__ out) {
    int b = blockIdx.x;
    int tid = threadIdx.x;                     // 128 threads
    __shared__ float mid[Dn];
    float sv = 0.f;
    for (int c = 0; c < 32; ++c) sv += part[(size_t)(b * 32 + c) * Dn + tid];
    mid[tid] = sv;
    __syncthreads();
    if (tid < OUTn) {
        float o = bout[tid];
        #pragma unroll 4
        for (int k = 0; k < Dn; ++k) o = fmaf(mid[k], Wout[k * OUTn + tid], o);
        out[b * OUTn + tid] = o;
    }
}

// ---------------------------------------------------------------------------
extern "C" void kernel_launch(void* const* d_in, const int* in_sizes, int n_in,
                              void* d_out, int out_size, void* d_ws, size_t ws_size,
                              hipStream_t stream) {
    const float* INPUT = (const float*)d_in[0];
    const float* CFG   = (const float*)d_in[1];
    // d_in[2] = LFG, unused by the forward pass
    const float* w1    = (const float*)d_in[3];
    const float* b1    = (const float*)d_in[4];
    const float* w2    = (const float*)d_in[5];
    const float* b2    = (const float*)d_in[6];
    const float* Wm    = (const float*)d_in[7];
    const float* Wout  = (const float*)d_in[8];
    const float* bout  = (const float*)d_in[9];
    float* out = (float*)d_out;

    // workspace layout (~18.7 MB)
    __half* xh   = (__half*)d_ws;                         // Sn*Nn*Dn   (4 MB)
    __half* xwh  = xh + (size_t)Sn * Nn * Dn;             // Sn*Nn*Dn   (4 MB)
    __half* WhT  = xwh + (size_t)Sn * Nn * Dn;            // Dn*Dn      (32 KB)
    int*    adj  = (int*)(WhT + (size_t)Dn * Dn);         // Sn*Nn*MAXDEG (8 MB)
    int*    deg  = adj + (size_t)Sn * Nn * MAXDEG;        // Sn*Nn
    float*  ah1a = (float*)(deg + Sn * Nn);               // Sn*Nn
    float*  ah2a = ah1a + Sn * Nn;                        // Sn*Nn
    float*  ah1b = ah2a + Sn * Nn;                        // Sn*Nn
    float*  ah2b = ah1b + Sn * Nn;                        // Sn*Nn
    float*  part = ah2b + Sn * Nn;                        // Bn*32*Dn
    unsigned long long* bits = (unsigned long long*)(part + Bn * 32 * Dn); // 2 MB

    fwd_bits_init<<<(Bn * Nn) / 4 + (Bn * Nn) / 8 + 1, 256, 0, stream>>>(
        (const float4*)CFG, bits, adj, deg, (const float4*)INPUT,
        xh, Wm, WhT, w1, b1, w2, b2, ah1a, ah2a);

    for (int it = 0; it < NITER; ++it) {
        if (it == 0) {
            gemm_rev<<<4096, 256, 0, stream>>>(xh, WhT, xwh, bits, adj, deg);
        } else {
            gemm_mfma<<<2048, 256, 0, stream>>>(xh, WhT, xwh);
        }
        const float* r1 = (it & 1) ? ah1b : ah1a;
        const float* r2 = (it & 1) ? ah2b : ah2a;
        float* w1p = (it & 1) ? ah1a : ah1b;
        float* w2p = (it & 1) ? ah2a : ah2b;
        attn_agg<<<(Sn * Nn) / 4, 256, 0, stream>>>(
            xh, xwh, adj, deg, r1, r2, w1p, w2p, w1, b1, w2, b2);
    }

    reduce_partial<<<Bn * 32, 128, 0, stream>>>(xh, part);
    final_out     <<<Bn, 128, 0, stream>>>(part, Wout, bout, out);
}